// Round 18
// baseline (6253.510 us; speedup 1.0000x reference)
//
#include <hip/hip_runtime.h>
#include <stdint.h>

// ---------- types ----------
typedef __attribute__((ext_vector_type(4))) float  f32x4;
typedef __attribute__((ext_vector_type(8))) _Float16 f16x8;
typedef __attribute__((ext_vector_type(8))) unsigned short u16x8;

__device__ __forceinline__ unsigned short f2h(float f) {
    _Float16 h = (_Float16)f;
    union { _Float16 h; unsigned short u; } cv; cv.h = h; return cv.u;
}

__device__ __forceinline__ f32x4 mfma16(f16x8 a, f16x8 b, f32x4 c) {
    return __builtin_amdgcn_mfma_f32_16x16x32_f16(a, b, c, 0, 0, 0);
}

// async global->LDS, 16B per lane. LDS dest is wave-uniform base; HW writes
// lane i at base + i*16.
__device__ __forceinline__ void async16(const unsigned short* g, unsigned short* l) {
    __builtin_amdgcn_global_load_lds(
        (const __attribute__((address_space(1))) unsigned int*)g,
        (__attribute__((address_space(3))) unsigned int*)l,
        16, 0, 0);
}

// =====================================================================
// GEMM: C(MxN) = A(MxK,f16 rowmajor) * Bw(NxK,f16 rowmajor == W^T)
// BM=64 x BN=128, 4 waves x 64x32 sub-tile, 2-buffer __syncthreads loop.
// BK template: 32 (measured best for K=768) / 64 (best for K=3072).
// f16-output epilogues (EPI 0 q/k, EPI 2) use an LDS-bounce (stride 136)
// so global stores are full-line u16x8 (RMW fix).
// EPI 1/3 (x += C + bias): fused LayerNorm tail — after fp32 stores,
// threadfence + per-64-row-panel atomic counter; last of the 6 n-blocks
// LNs rows [m0,m0+64) and writes xn (removes 23 ln_k dispatches and an
// extra x round-trip). Counter self-cleans to 0; memset at launch.
// EPI 0: QKV scatter+bias (V transposed [bh][d][208], scalar path)
// EPI 2: gelu    EPI 4: patch: x = C + b + pos
// =====================================================================
template<int EPI, int BK>
__global__ __launch_bounds__(256, (BK == 32 ? 4 : 3))
void gemm_k(const unsigned short* __restrict__ A, const unsigned short* __restrict__ Bw,
            int M, int K, int N,
            float* __restrict__ p0, unsigned short* __restrict__ p1,
            const float* __restrict__ p2, const float* __restrict__ p3,
            unsigned short* __restrict__ p4, unsigned short* __restrict__ p5,
            const float* __restrict__ lngs, const float* __restrict__ lngb,
            unsigned short* __restrict__ xnout, int* __restrict__ cnt)
{
    constexpr int SMSTG = 2 * 64 * BK + 2 * 128 * BK;  // lA | lB staging (u16)
    constexpr int SMU   = (EPI == 0 || EPI == 2)
                          ? (SMSTG > 64 * 136 ? SMSTG : 64 * 136)
                          : SMSTG;
    __shared__ unsigned short smem[SMU];
    unsigned short (*lA)[64 * BK]  = (unsigned short(*)[64 * BK])smem;
    unsigned short (*lB)[128 * BK] = (unsigned short(*)[128 * BK])(smem + 2 * 64 * BK);
    const int tid  = threadIdx.x;
    const int lane = tid & 63;
    const int wid  = tid >> 6;

    // ---- XCD-bijective swizzle (m204) ----
    const int gx  = gridDim.x;
    const int nwg = gx * gridDim.y;
    const int lin = blockIdx.y * gx + blockIdx.x;
    const int q = nwg >> 3, r = nwg & 7;
    const int xcd = lin & 7, i = lin >> 3;
    const int wg  = (xcd < r ? xcd * (q + 1) : r * (q + 1) + (xcd - r) * q) + i;
    const int m0 = (wg / gx) * 64;
    const int n0 = (wg % gx) * 128;

    const int colBase = wid * 32;          // wave's 32-col window
    const int fr = lane & 15, fg = lane >> 4;

    f32x4 acc[4][2];
#pragma unroll
    for (int a = 0; a < 4; ++a)
#pragma unroll
        for (int b = 0; b < 2; ++b) acc[a][b] = (f32x4){0.f, 0.f, 0.f, 0.f};

    const int nk = K / BK;
    constexpr int CPR = BK / 8;            // 16B chunks per row (4 or 8)
    constexpr int ACH = 64 * CPR;          // A chunks (256 or 512)
    constexpr int NH  = (ACH + 128 * CPR) / 256;  // stage iters (3 or 6)

    auto stage = [&](int buf, int kt) {
        const int k0 = kt * BK;
#pragma unroll
        for (int h = 0; h < NH; ++h) {
            const int c = h * 256 + tid;
            const int wbase = h * 256 + wid * 64;
            if (c < ACH) {
                const int row = c / CPR, kc = c % CPR;
                const int gkc = (BK == 32) ? (kc ^ ((row >> 1) & 3)) : (kc ^ (row & 7));
                int ar = m0 + row; if (ar > M - 1) ar = M - 1;
                async16(A + (size_t)ar * K + k0 + gkc * 8,
                        &lA[buf][(size_t)wbase * 8]);
            } else {
                const int cb = c - ACH;
                const int row = cb / CPR, kc = cb % CPR;
                const int gkc = (BK == 32) ? (kc ^ ((row >> 1) & 3)) : (kc ^ (row & 7));
                async16(Bw + (size_t)(n0 + row) * K + k0 + gkc * 8,
                        &lB[buf][(size_t)(wbase - ACH) * 8]);
            }
        }
    };

    stage(0, 0);
    for (int kt = 0; kt < nk; ++kt) {
        __syncthreads();                   // drains vmcnt(0): buf ready
        if (kt + 1 < nk) stage((kt + 1) & 1, kt + 1);
        const int buf = kt & 1;
#pragma unroll
        for (int kk = 0; kk < BK / 32; ++kk) {   // k ascending
            f16x8 af[4], bfv[2];
#pragma unroll
            for (int mi = 0; mi < 4; ++mi) {
                int row = mi * 16 + fr;
                int pc  = (BK == 32) ? (fg ^ ((row >> 1) & 3))
                                     : ((kk * 4 + fg) ^ (row & 7));
                af[mi] = *(const f16x8*)(&lA[buf][row * BK + pc * 8]);
            }
#pragma unroll
            for (int ni = 0; ni < 2; ++ni) {
                int row = colBase + ni * 16 + fr;
                int pc  = (BK == 32) ? (fg ^ ((row >> 1) & 3))
                                     : ((kk * 4 + fg) ^ (row & 7));
                bfv[ni] = *(const f16x8*)(&lB[buf][row * BK + pc * 8]);
            }
#pragma unroll
            for (int mi = 0; mi < 4; ++mi)
#pragma unroll
                for (int ni = 0; ni < 2; ++ni)
                    acc[mi][ni] = mfma16(af[mi], bfv[ni], acc[mi][ni]);
        }
    }

    // ---------------- epilogue ----------------
    // C/D layout: col = lane&15, row = 4*(lane>>4)+reg  [m89]
    const int mat0 = (EPI == 0) ? (n0 / 768) : 0;   // block-uniform

    if constexpr (EPI == 0 || EPI == 2) {
        if (EPI == 2 || mat0 < 2) {
            // LDS-bounce (stride 136): full-line u16x8 global stores
            unsigned short* sm = smem;
            __syncthreads();
#pragma unroll
            for (int mi = 0; mi < 4; ++mi)
#pragma unroll
                for (int ni = 0; ni < 2; ++ni) {
                    const int lcol = colBase + ni * 16 + fr;
                    const int colg = n0 + lcol;
#pragma unroll
                    for (int reg = 0; reg < 4; ++reg) {
                        const int lrow = mi * 16 + fg * 4 + reg;
                        float val = acc[mi][ni][reg] + p2[colg];
                        if (EPI == 2)
                            val = 0.5f * val * (1.0f + erff(val * 0.70710678118654752f));
                        sm[lrow * 136 + lcol] = f2h(val);
                    }
                }
            __syncthreads();
#pragma unroll
            for (int it = 0; it < 4; ++it) {
                const int e = it * 256 + tid;       // 1024 chunks of 8
                const int lrow = e >> 4, cch = e & 15;
                const int grow = m0 + lrow;
                if (grow >= M) continue;
                const u16x8 v = *(const u16x8*)(&sm[lrow * 136 + cch * 8]);
                if (EPI == 2) {
                    *(u16x8*)(p1 + (size_t)grow * 3072 + n0 + cch * 8) = v;
                } else {
                    const int colg = n0 + cch * 8;
                    const int w = colg - mat0 * 768;
                    const int h = w >> 6, d = w & 63;
                    const int b = grow / 197, s = grow - b * 197;
                    unsigned short* dst = (mat0 == 0) ? p1 : p4;
                    *(u16x8*)(dst + ((((size_t)b * 12 + h) * 197 + s) * 64 + d)) = v;
                }
            }
        } else {
            // V (mat==2): transposed target, scalar path
#pragma unroll
            for (int mi = 0; mi < 4; ++mi)
#pragma unroll
                for (int ni = 0; ni < 2; ++ni) {
                    const int col = n0 + colBase + ni * 16 + fr;
                    const int w = col - 1536;
                    const int h = w >> 6, d = w & 63;
#pragma unroll
                    for (int reg = 0; reg < 4; ++reg) {
                        const int row = m0 + mi * 16 + fg * 4 + reg;
                        if (row >= M) continue;
                        const int b = row / 197, s = row - b * 197;
                        float val = acc[mi][ni][reg] + p2[col];
                        p5[(((size_t)b * 12 + h) * 64 + d) * 208 + s] = f2h(val);
                    }
                }
        }
    } else {
#pragma unroll
        for (int mi = 0; mi < 4; ++mi) {
#pragma unroll
            for (int ni = 0; ni < 2; ++ni) {
                const int col = n0 + colBase + ni * 16 + fr;
#pragma unroll
                for (int reg = 0; reg < 4; ++reg) {
                    const int row = m0 + mi * 16 + fg * 4 + reg;
                    if (row >= M) continue;
                    const float v = acc[mi][ni][reg];
                    if constexpr (EPI == 1 || EPI == 3) {
                        size_t idx = (size_t)row * 768 + col;
                        p0[idx] = p0[idx] + v + p2[col];
                    } else { // EPI == 4
                        int b = row / 196, p = row - b * 196;
                        float val = v + p2[col] + p3[(size_t)(1 + p) * 768 + col];
                        p0[((size_t)(b * 197 + 1 + p)) * 768 + col] = val;
                    }
                }
            }
        }
    }

    // ---------------- fused LayerNorm tail (EPI 1/3) ----------------
    if constexpr (EPI == 1 || EPI == 3) {
        if (lngs != nullptr) {
            __shared__ int lastFlag;
            __threadfence();                       // release x writes
            if (tid == 0) {
                int old = atomicAdd(&cnt[m0 >> 6], 1);
                lastFlag = (old == (int)gridDim.x - 1) ? 1 : 0;
            }
            __syncthreads();
            if (lastFlag) {
                __threadfence();                   // acquire others' writes
                for (int rr = wid; rr < 64; rr += 4) {
                    const int row = m0 + rr;
                    if (row >= M) continue;
                    const float* xr = p0 + (size_t)row * 768;
                    float s = 0.f, q2 = 0.f;
                    for (int c = lane; c < 768; c += 64) {
                        float v = xr[c]; s += v; q2 += v * v;
                    }
#pragma unroll
                    for (int o = 1; o < 64; o <<= 1) {
                        s += __shfl_xor(s, o); q2 += __shfl_xor(q2, o);
                    }
                    const float mean = s * (1.0f / 768.0f);
                    const float rstd = rsqrtf(q2 * (1.0f / 768.0f) - mean * mean + 1e-5f);
                    unsigned short* orow = xnout + (size_t)row * 768;
                    for (int c = lane; c < 768; c += 64)
                        orow[c] = f2h((xr[c] - mean) * rstd * lngs[c] + lngb[c]);
                }
                if (tid == 0) cnt[m0 >> 6] = 0;    // self-clean
            }
        }
    }
}

// =====================================================================
// Transpose-convert body: src fp32 [K][N] -> dst f16 [N][K], 64x64 tile.
// =====================================================================
__device__ __forceinline__ void convT_body(const float* __restrict__ src,
                                           unsigned short* __restrict__ dst,
                                           int K, int N, int bx, int by,
                                           float (*t)[65])
{
    const int tid = threadIdx.x;
    const int n0 = bx * 64, k0 = by * 64;
    int r = tid >> 4, cq = tid & 15;
#pragma unroll
    for (int i = 0; i < 4; ++i) {
        f32x4 v = *(const f32x4*)(src + (size_t)(k0 + r + i * 16) * N + n0 + cq * 4);
        t[r + i * 16][cq * 4 + 0] = v.x;
        t[r + i * 16][cq * 4 + 1] = v.y;
        t[r + i * 16][cq * 4 + 2] = v.z;
        t[r + i * 16][cq * 4 + 3] = v.w;
    }
    __syncthreads();
    int nl = tid >> 2, kq = tid & 3;
    u16x8 o0, o1;
#pragma unroll
    for (int j = 0; j < 8; ++j) {
        o0[j] = f2h(t[kq * 16 + j][nl]);
        o1[j] = f2h(t[kq * 16 + 8 + j][nl]);
    }
    unsigned short* d = dst + (size_t)(n0 + nl) * K + k0 + kq * 16;
    *(u16x8*)(d)     = o0;
    *(u16x8*)(d + 8) = o1;
}

// prep block decode (pid in [0,1729)): all 6 weight transposes + bias pack
__device__ __forceinline__ void prep_block(int pid,
            const float* __restrict__ wq, const float* __restrict__ wk,
            const float* __restrict__ wv, const float* __restrict__ wo,
            const float* __restrict__ w1, const float* __restrict__ w2,
            const float* __restrict__ bq, const float* __restrict__ bk,
            const float* __restrict__ bv,
            unsigned short* __restrict__ wqkvT, unsigned short* __restrict__ woT,
            unsigned short* __restrict__ w1T, unsigned short* __restrict__ w2T,
            float* __restrict__ bqkv, float (*t)[65])
{
    if (pid == 1728) {
        for (int c = threadIdx.x; c < 2304; c += 256) {
            int m = c / 768, w = c - m * 768;
            bqkv[c] = (m == 0) ? bq[w] : (m == 1 ? bk[w] : bv[w]);
        }
        return;
    }
    const float* src; unsigned short* dst; int K, N, bx, by;
    if (pid < 576) {
        int mat = pid / 144, r = pid - mat * 144;
        K = 768; N = 768; bx = r % 12; by = r / 12;
        if (mat == 0)      { src = wq; dst = wqkvT; }
        else if (mat == 1) { src = wk; dst = wqkvT + 768ull * 768; }
        else if (mat == 2) { src = wv; dst = wqkvT + 1536ull * 768; }
        else               { src = wo; dst = woT; }
    } else if (pid < 1152) {
        int r = pid - 576; K = 768; N = 3072; bx = r % 48; by = r / 48;
        src = w1; dst = w1T;
    } else {
        int r = pid - 1152; K = 3072; N = 768; bx = r % 12; by = r / 12;
        src = w2; dst = w2T;
    }
    convT_body(src, dst, K, N, bx, by, t);
}

// standalone prep (layer 0, pre-loop)
__global__ __launch_bounds__(256)
void prep_k(const float* __restrict__ wq, const float* __restrict__ wk,
            const float* __restrict__ wv, const float* __restrict__ wo,
            const float* __restrict__ w1, const float* __restrict__ w2,
            const float* __restrict__ bq, const float* __restrict__ bk,
            const float* __restrict__ bv,
            unsigned short* __restrict__ wqkvT, unsigned short* __restrict__ woT,
            unsigned short* __restrict__ w1T, unsigned short* __restrict__ w2T,
            float* __restrict__ bqkv)
{
    __shared__ float t[64][65];
    prep_block(blockIdx.x, wq, wk, wv, wo, w1, w2, bq, bk, bv,
               wqkvT, woT, w1T, w2T, bqkv, t);
}

// =====================================================================
// attn_prep_k: flattened grid = 2688 attn blocks + nprep prep blocks.
// attn: no K/V LDS staging; K from global (L2), V pre-transposed.
// prep blocks transpose layer-(l+1) weights into the other dbuf set.
// =====================================================================
__global__ __launch_bounds__(256, 4)
void attn_prep_k(const unsigned short* __restrict__ qb, const unsigned short* __restrict__ kb,
                 const unsigned short* __restrict__ vt, unsigned short* __restrict__ ao,
                 const float* __restrict__ wq, const float* __restrict__ wk,
                 const float* __restrict__ wv, const float* __restrict__ wo,
                 const float* __restrict__ w1, const float* __restrict__ w2,
                 const float* __restrict__ bq, const float* __restrict__ bk,
                 const float* __restrict__ bv,
                 unsigned short* __restrict__ wqkvT, unsigned short* __restrict__ woT,
                 unsigned short* __restrict__ w1T, unsigned short* __restrict__ w2T,
                 float* __restrict__ bqkv)
{
    __shared__ float smbuf[32 * 210 + 32];   // attn sc+rinv / prep tile

    const int bid = blockIdx.x;
    if (bid >= 2688) {
        prep_block(bid - 2688, wq, wk, wv, wo, w1, w2, bq, bk, bv,
                   wqkvT, woT, w1T, w2T, bqkv,
                   reinterpret_cast<float(*)[65]>(smbuf));
        return;
    }

    float* sc   = smbuf;
    float* rinv = smbuf + 32 * 210;

    const int bh = bid % 384;
    const int qt = bid / 384;
    const int b = bh / 12, h = bh - b * 12;
    const unsigned short* qh  = qb + (size_t)bh * 197 * 64;
    const unsigned short* kh  = kb + (size_t)bh * 197 * 64;
    const unsigned short* vth = vt + (size_t)bh * 64 * 208;
    const int tid = threadIdx.x, lane = tid & 63, wid = tid >> 6;
    const int fr = lane & 15, fg = lane >> 4;

    f16x8 qf[2][2];
#pragma unroll
    for (int mi = 0; mi < 2; ++mi)
#pragma unroll
        for (int kc = 0; kc < 2; ++kc) {
            int s = qt * 32 + mi * 16 + fr; if (s > 196) s = 196;
            qf[mi][kc] = *(const f16x8*)(qh + (size_t)s * 64 + kc * 32 + fg * 8);
        }

    for (int nt = wid; nt < 13; nt += 4) {
        f32x4 a0 = (f32x4){0.f,0.f,0.f,0.f}, a1 = a0;
        int rs = nt * 16 + fr; if (rs > 196) rs = 196;
#pragma unroll
        for (int kc = 0; kc < 2; ++kc) {
            f16x8 kf = *(const f16x8*)(kh + (size_t)rs * 64 + kc * 32 + fg * 8);
            a0 = mfma16(qf[0][kc], kf, a0);
            a1 = mfma16(qf[1][kc], kf, a1);
        }
        int ccol = nt * 16 + fr;
        bool valid = (ccol < 197);
#pragma unroll
        for (int reg = 0; reg < 4; ++reg) {
            int mr = fg * 4 + reg;
            sc[mr * 210 + ccol]        = valid ? a0[reg] * 0.125f : -1e30f;
            sc[(16 + mr) * 210 + ccol] = valid ? a1[reg] * 0.125f : -1e30f;
        }
    }
    __syncthreads();

    {
        int row = tid >> 3, j = tid & 7;
        float m = -1e30f;
        for (int c = j; c < 208; c += 8) m = fmaxf(m, sc[row * 210 + c]);
#pragma unroll
        for (int o = 1; o < 8; o <<= 1) m = fmaxf(m, __shfl_xor(m, o));
        float sum = 0.f;
        for (int c = j; c < 208; c += 8) {
            float e = __expf(sc[row * 210 + c] - m);
            sc[row * 210 + c] = e;
            sum += e;
        }
#pragma unroll
        for (int o = 1; o < 8; o <<= 1) sum += __shfl_xor(sum, o);
        if (j == 0) rinv[row] = 1.0f / sum;
    }
    __syncthreads();

    f32x4 o0 = (f32x4){0.f,0.f,0.f,0.f}, o1 = o0;
    const int dbase = wid * 16;
    for (int kt = 0; kt < 7; ++kt) {
        int kb8 = kt * 32 + fg * 8;
        f16x8 pa0, pa1, vf;
        if (kb8 >= 208) {
#pragma unroll
            for (int j = 0; j < 8; ++j) { pa0[j] = (_Float16)0.f; pa1[j] = (_Float16)0.f; vf[j] = (_Float16)0.f; }
        } else {
            const float* pr0 = &sc[fr * 210 + kb8];
            const float* pr1 = &sc[(16 + fr) * 210 + kb8];
#pragma unroll
            for (int j = 0; j < 8; ++j) { pa0[j] = (_Float16)pr0[j]; pa1[j] = (_Float16)pr1[j]; }
            vf = *(const f16x8*)(vth + (size_t)(dbase + fr) * 208 + kb8);
        }
        o0 = mfma16(pa0, vf, o0);
        o1 = mfma16(pa1, vf, o1);
    }
#pragma unroll
    for (int reg = 0; reg < 4; ++reg) {
        int mr0 = fg * 4 + reg, s0 = qt * 32 + mr0;
        if (s0 < 197)
            ao[((size_t)(b * 197 + s0)) * 768 + h * 64 + dbase + fr] = f2h(o0[reg] * rinv[mr0]);
        int mr1 = 16 + fg * 4 + reg, s1 = qt * 32 + mr1;
        if (s1 < 197)
            ao[((size_t)(b * 197 + s1)) * 768 + h * 64 + dbase + fr] = f2h(o1[reg] * rinv[mr1]);
    }
}

// =====================================================================
// LayerNorm: fp32 in -> f16 out, one row/block (layer-0 ln1 only)
// =====================================================================
__global__ __launch_bounds__(256, 4)
void ln_k(const float* __restrict__ x, const float* __restrict__ gs,
          const float* __restrict__ gb, unsigned short* __restrict__ out)
{
    const int row = blockIdx.x;
    const int tid = threadIdx.x, lane = tid & 63, wid = tid >> 6;
    const float* xr = x + (size_t)row * 768;
    float v0 = xr[tid], v1 = xr[tid + 256], v2 = xr[tid + 512];
    float s = v0 + v1 + v2;
    float q = v0 * v0 + v1 * v1 + v2 * v2;
#pragma unroll
    for (int o = 1; o < 64; o <<= 1) { s += __shfl_xor(s, o); q += __shfl_xor(q, o); }
    __shared__ float ws[4], wq[4];
    if (lane == 0) { ws[wid] = s; wq[wid] = q; }
    __syncthreads();
    s = ws[0] + ws[1] + ws[2] + ws[3];
    q = wq[0] + wq[1] + wq[2] + wq[3];
    const float mean = s * (1.0f / 768.0f);
    const float rstd = rsqrtf(q * (1.0f / 768.0f) - mean * mean + 1e-5f);
    unsigned short* orow = out + (size_t)row * 768;
    orow[tid]       = f2h((v0 - mean) * rstd * gs[tid]       + gb[tid]);
    orow[tid + 256] = f2h((v1 - mean) * rstd * gs[tid + 256] + gb[tid + 256]);
    orow[tid + 512] = f2h((v2 - mean) * rstd * gs[tid + 512] + gb[tid + 512]);
}

__global__ __launch_bounds__(256)
void convT_k(const float* __restrict__ src, unsigned short* __restrict__ dst, int K, int N)
{
    __shared__ float t[64][65];
    convT_body(src, dst, K, N, blockIdx.x, blockIdx.y, t);
}

// patches: [6272][768] f16, col = (py*16+px)*3 + c
__global__ __launch_bounds__(256)
void patch_k(const float* __restrict__ img, unsigned short* __restrict__ patches)
{
    const int t = blockIdx.x;
    const int pxy = threadIdx.x;
    const int b = t / 196, pi = t - b * 196;
    const int gy = pi / 14, gx = pi - gy * 14;
    const int py = pxy >> 4, px = pxy & 15;
    const int yy = gy * 16 + py, xx = gx * 16 + px;
    const float* base = img + ((size_t)b * 3 * 224 + yy) * 224 + xx;
    float c0 = base[0];
    float c1 = base[224 * 224];
    float c2 = base[2 * 224 * 224];
    unsigned short* d = patches + (size_t)t * 768 + pxy * 3;
    d[0] = f2h(c0); d[1] = f2h(c1); d[2] = f2h(c2);
}

__global__ void cls_k(const float* __restrict__ cls, const float* __restrict__ pos,
                      float* __restrict__ x)
{
    int c = blockIdx.x * 256 + threadIdx.x;   // 0..767
    int b = blockIdx.y;
    x[((size_t)b * 197) * 768 + c] = cls[c] + pos[c];
}

// final LN on cls row + head matmul. grid (8 n-tiles of 125, 32 b).
__global__ __launch_bounds__(256, 4)
void head_k(const float* __restrict__ x, const float* __restrict__ fs, const float* __restrict__ fb,
            const float* __restrict__ hw, const float* __restrict__ hb, float* __restrict__ out)
{
    __shared__ float xn[768];
    __shared__ float ws[4], wq_[4];
    const int b  = blockIdx.y;
    const int n0 = blockIdx.x * 125;
    const int tid = threadIdx.x, lane = tid & 63, wid = tid >> 6;
    const float* xr = x + (size_t)b * 197 * 768;
    float v0 = xr[tid], v1 = xr[tid + 256], v2 = xr[tid + 512];
    float s = v0 + v1 + v2, q = v0 * v0 + v1 * v1 + v2 * v2;
#pragma unroll
    for (int o = 1; o < 64; o <<= 1) { s += __shfl_xor(s, o); q += __shfl_xor(q, o); }
    if (lane == 0) { ws[wid] = s; wq_[wid] = q; }
    __syncthreads();
    s = ws[0] + ws[1] + ws[2] + ws[3];
    q = wq_[0] + wq_[1] + wq_[2] + wq_[3];
    float mean = s * (1.f / 768.f);
    float rstd = rsqrtf(q * (1.f / 768.f) - mean * mean + 1e-5f);
    xn[tid]       = (v0 - mean) * rstd * fs[tid]       + fb[tid];
    xn[tid + 256] = (v1 - mean) * rstd * fs[tid + 256] + fb[tid + 256];
    xn[tid + 512] = (v2 - mean) * rstd * fs[tid + 512] + fb[tid + 512];
    __syncthreads();

    const int nrel = tid >> 1, half = tid & 1;
    const int n = n0 + nrel;
    float acc = 0.f;
    if (nrel < 125) {
        const float* hp = hw + (size_t)(half * 384) * 1000 + n;
        const float* xp = xn + half * 384;
#pragma unroll 4
        for (int k = 0; k < 384; ++k) acc = fmaf(xp[k], hp[(size_t)k * 1000], acc);
    }
    acc += __shfl_xor(acc, 1);
    if (half == 0 && nrel < 125) out[(size_t)b * 1000 + n] = acc + hb[n];
}

// =====================================================================
extern "C" void kernel_launch(void* const* d_in, const int* in_sizes, int n_in,
                              void* d_out, int out_size, void* d_ws, size_t ws_size,
                              hipStream_t stream)
{
    (void)in_sizes; (void)n_in; (void)out_size; (void)ws_size;
    const float* img    = (const float*)d_in[0];
    const float* proj_w = (const float*)d_in[1];
    const float* proj_b = (const float*)d_in[2];
    const float* cls_t  = (const float*)d_in[3];
    const float* pos    = (const float*)d_in[4];
    const float* ln1_s  = (const float*)d_in[5];
    const float* ln1_b  = (const float*)d_in[6];
    const float* wq     = (const float*)d_in[7];
    const float* bq     = (const float*)d_in[8];
    const float* wk     = (const float*)d_in[9];
    const float* bk     = (const float*)d_in[10];
    const float* wv     = (const float*)d_in[11];
    const float* bv     = (const float*)d_in[12];
    const float* wo     = (const float*)d_in[13];
    const float* bo     = (const float*)d_in[14];
    const float* ln2_s  = (const float*)d_in[15];
    const float* ln2_b  = (const float*)d_in[16];
    const float* w1     = (const float*)d_in[17];
    const float* b1     = (const float*)d_in[18];
    const float* w2     = (const float*)d_in[19];
    const float* b2     = (const float*)d_in[20];
    const float* fs     = (const float*)d_in[21];
    const float* fb     = (const float*)d_in[22];
    const float* hw     = (const float*)d_in[23];
    const float* hb     = (const float*)d_in[24];

    char* ws = (char*)d_ws;
    size_t off = 0;
    auto alloc = [&](size_t bytes) -> char* {
        char* r = ws + off;
        off += (bytes + 255) & ~(size_t)255;
        return r;
    };
    // double-buffered transposed-weight sets (layer parity)
    unsigned short* wqkvT[2]; unsigned short* woT[2];
    unsigned short* w1T[2];   unsigned short* w2T[2];
    float* bqkv[2];
    for (int s = 0; s < 2; ++s) {
        wqkvT[s] = (unsigned short*)alloc(2304ull * 768 * 2);
        woT[s]   = (unsigned short*)alloc(768ull * 768 * 2);
        w1T[s]   = (unsigned short*)alloc(3072ull * 768 * 2);
        w2T[s]   = (unsigned short*)alloc(768ull * 3072 * 2);
        bqkv[s]  = (float*)alloc(2304 * 4);
    }
    unsigned short* projT = (unsigned short*)alloc(768ull * 768 * 2);
    float*          x     = (float*)alloc(6304ull * 768 * 4);
    unsigned short* xn    = (unsigned short*)alloc(6304ull * 768 * 2);
    unsigned short* qbuf  = (unsigned short*)alloc(4841472ull * 2);
    unsigned short* kbuf  = (unsigned short*)alloc(4841472ull * 2);
    unsigned short* vbufT = (unsigned short*)alloc(384ull * 64 * 208 * 2); // [bh][d][208]
    unsigned short* aob   = (unsigned short*)alloc(6304ull * 768 * 2);
    unsigned short* hbuf  = (unsigned short*)alloc(6304ull * 3072 * 2);
    int*            lncnt = (int*)alloc(128 * 4);   // per-64-row-panel counters
    unsigned short* patches = hbuf; // alias: only used before layer loop

    // zero LN-tail counters (poisoned 0xAA before first timed call)
    hipMemsetAsync(lncnt, 0, 128 * 4, stream);

    // ---- patch embedding + layer-0 weight prep ----
    convT_k<<<dim3(12, 12), 256, 0, stream>>>(proj_w, projT, 768, 768);
    patch_k<<<dim3(6272), 256, 0, stream>>>(img, patches);
    prep_k<<<dim3(1729), 256, 0, stream>>>(
        wq, wk, wv, wo, w1, w2, bq, bk, bv,
        wqkvT[0], woT[0], w1T[0], w2T[0], bqkv[0]);
    gemm_k<4, 32><<<dim3(6, 98), 256, 0, stream>>>(patches, projT, 6272, 768, 768,
                                                   x, nullptr, proj_b, pos, nullptr, nullptr,
                                                   nullptr, nullptr, nullptr, nullptr);
    cls_k<<<dim3(3, 32), 256, 0, stream>>>(cls_t, pos, x);

    // layer-0 ln1 (standalone; later LNs are fused into GEMM tails)
    ln_k<<<dim3(6304), 256, 0, stream>>>(x, ln1_s, ln1_b, xn);

    // ---- transformer layers ----
    for (int l = 0; l < 12; ++l) {
        const int set = l & 1, nxt = set ^ 1;
        const int lp  = (l < 11) ? l + 1 : 11;       // prep source layer
        const int nprep = (l < 11) ? 1729 : 0;

        gemm_k<0, 32><<<dim3(18, 99), 256, 0, stream>>>(xn, wqkvT[set], 6304, 768, 2304,
                                                        nullptr, qbuf, bqkv[set], nullptr, kbuf, vbufT,
                                                        nullptr, nullptr, nullptr, nullptr);
        attn_prep_k<<<dim3(2688 + nprep), 256, 0, stream>>>(
            qbuf, kbuf, vbufT, aob,
            wq + (size_t)lp * 768 * 768, wk + (size_t)lp * 768 * 768,
            wv + (size_t)lp * 768 * 768, wo + (size_t)lp * 768 * 768,
            w1 + (size_t)lp * 768 * 3072, w2 + (size_t)lp * 3072 * 768,
            bq + lp * 768, bk + lp * 768, bv + lp * 768,
            wqkvT[nxt], woT[nxt], w1T[nxt], w2T[nxt], bqkv[nxt]);
        // OPROJ: x += C + bo, fused ln2(l) -> xn
        gemm_k<1, 32><<<dim3(6, 99), 256, 0, stream>>>(aob, woT[set], 6304, 768, 768,
                                                       x, nullptr, bo + l * 768, nullptr, nullptr, nullptr,
                                                       ln2_s + l * 768, ln2_b + l * 768, xn, lncnt);
        gemm_k<2, 32><<<dim3(24, 99), 256, 0, stream>>>(xn, w1T[set], 6304, 768, 3072,
                                                        nullptr, hbuf, b1 + l * 3072, nullptr, nullptr, nullptr,
                                                        nullptr, nullptr, nullptr, nullptr);
        // MLP2: x += C + b2, fused ln1(l+1) -> xn (skip on last layer)
        const float* ngs = (l < 11) ? (ln1_s + (l + 1) * 768) : nullptr;
        const float* ngb = (l < 11) ? (ln1_b + (l + 1) * 768) : nullptr;
        gemm_k<3, 64><<<dim3(6, 99), 256, 0, stream>>>(hbuf, w2T[set], 6304, 3072, 768,
                                                       x, nullptr, b2 + l * 768, nullptr, nullptr, nullptr,
                                                       ngs, ngb, xn, lncnt);
    }

    // ---- final LN (cls rows) + classifier head ----
    head_k<<<dim3(8, 32), 256, 0, stream>>>(x, fs, fb, hw, hb, (float*)d_out);
}

// Round 19
// 3036.770 us; speedup vs baseline: 2.0593x; 2.0593x over previous
//
#include <hip/hip_runtime.h>
#include <stdint.h>

// ---------- types ----------
typedef __attribute__((ext_vector_type(4))) float  f32x4;
typedef __attribute__((ext_vector_type(8))) _Float16 f16x8;
typedef __attribute__((ext_vector_type(8))) unsigned short u16x8;

__device__ __forceinline__ unsigned short f2h(float f) {
    _Float16 h = (_Float16)f;
    union { _Float16 h; unsigned short u; } cv; cv.h = h; return cv.u;
}

__device__ __forceinline__ f32x4 mfma16(f16x8 a, f16x8 b, f32x4 c) {
    return __builtin_amdgcn_mfma_f32_16x16x32_f16(a, b, c, 0, 0, 0);
}

// async global->LDS, 16B per lane. LDS dest is wave-uniform base; HW writes
// lane i at base + i*16.
__device__ __forceinline__ void async16(const unsigned short* g, unsigned short* l) {
    __builtin_amdgcn_global_load_lds(
        (const __attribute__((address_space(1))) unsigned int*)g,
        (__attribute__((address_space(3))) unsigned int*)l,
        16, 0, 0);
}

// =====================================================================
// GEMM: C(MxN) = A(MxK,f16 rowmajor) * Bw(NxK,f16 rowmajor == W^T)
// BM=64 x BN=128, 4 waves x 64x32 sub-tile, 2-buffer __syncthreads loop.
// BK template: 32 (measured best for K=768) / 64 (best for K=3072).
// Both A and B LDS-staged (R16 proved direct-global B is uncoalesced
// and latency-bound). f16-output epilogues (EPI 0 q/k, EPI 2) use an
// LDS-bounce with stride 136 (u16x8-aligned, ~4-way banks) so global
// stores are full-line u16x8 (RMW fix, R15/R17). LN stays standalone
// (R18 proved cross-block LN tails with threadfence are catastrophic).
// EPI 0: QKV scatter+bias (V transposed [bh][d][208], scalar path)
// EPI 1/3: x += C + bias    EPI 2: gelu    EPI 4: patch: x = C + b + pos
// =====================================================================
template<int EPI, int BK>
__global__ __launch_bounds__(256, (BK == 32 ? 4 : 3))
void gemm_k(const unsigned short* __restrict__ A, const unsigned short* __restrict__ Bw,
            int M, int K, int N,
            float* __restrict__ p0, unsigned short* __restrict__ p1,
            const float* __restrict__ p2, const float* __restrict__ p3,
            unsigned short* __restrict__ p4, unsigned short* __restrict__ p5)
{
    constexpr int SMSTG = 2 * 64 * BK + 2 * 128 * BK;  // lA | lB staging (u16)
    constexpr int SMU   = (EPI == 0 || EPI == 2)
                          ? (SMSTG > 64 * 136 ? SMSTG : 64 * 136)
                          : SMSTG;
    __shared__ unsigned short smem[SMU];
    unsigned short (*lA)[64 * BK]  = (unsigned short(*)[64 * BK])smem;
    unsigned short (*lB)[128 * BK] = (unsigned short(*)[128 * BK])(smem + 2 * 64 * BK);
    const int tid  = threadIdx.x;
    const int lane = tid & 63;
    const int wid  = tid >> 6;

    // ---- XCD-bijective swizzle (m204) ----
    const int gx  = gridDim.x;
    const int nwg = gx * gridDim.y;
    const int lin = blockIdx.y * gx + blockIdx.x;
    const int q = nwg >> 3, r = nwg & 7;
    const int xcd = lin & 7, i = lin >> 3;
    const int wg  = (xcd < r ? xcd * (q + 1) : r * (q + 1) + (xcd - r) * q) + i;
    const int m0 = (wg / gx) * 64;
    const int n0 = (wg % gx) * 128;

    const int colBase = wid * 32;          // wave's 32-col window
    const int fr = lane & 15, fg = lane >> 4;

    f32x4 acc[4][2];
#pragma unroll
    for (int a = 0; a < 4; ++a)
#pragma unroll
        for (int b = 0; b < 2; ++b) acc[a][b] = (f32x4){0.f, 0.f, 0.f, 0.f};

    const int nk = K / BK;
    constexpr int CPR = BK / 8;            // 16B chunks per row (4 or 8)
    constexpr int ACH = 64 * CPR;          // A chunks (256 or 512)
    constexpr int NH  = (ACH + 128 * CPR) / 256;  // stage iters (3 or 6)

    auto stage = [&](int buf, int kt) {
        const int k0 = kt * BK;
#pragma unroll
        for (int h = 0; h < NH; ++h) {
            const int c = h * 256 + tid;
            const int wbase = h * 256 + wid * 64;
            if (c < ACH) {
                const int row = c / CPR, kc = c % CPR;
                const int gkc = (BK == 32) ? (kc ^ ((row >> 1) & 3)) : (kc ^ (row & 7));
                int ar = m0 + row; if (ar > M - 1) ar = M - 1;
                async16(A + (size_t)ar * K + k0 + gkc * 8,
                        &lA[buf][(size_t)wbase * 8]);
            } else {
                const int cb = c - ACH;
                const int row = cb / CPR, kc = cb % CPR;
                const int gkc = (BK == 32) ? (kc ^ ((row >> 1) & 3)) : (kc ^ (row & 7));
                async16(Bw + (size_t)(n0 + row) * K + k0 + gkc * 8,
                        &lB[buf][(size_t)(wbase - ACH) * 8]);
            }
        }
    };

    stage(0, 0);
    for (int kt = 0; kt < nk; ++kt) {
        __syncthreads();                   // drains vmcnt(0): buf ready
        if (kt + 1 < nk) stage((kt + 1) & 1, kt + 1);
        const int buf = kt & 1;
#pragma unroll
        for (int kk = 0; kk < BK / 32; ++kk) {   // k ascending
            f16x8 af[4], bfv[2];
#pragma unroll
            for (int mi = 0; mi < 4; ++mi) {
                int row = mi * 16 + fr;
                int pc  = (BK == 32) ? (fg ^ ((row >> 1) & 3))
                                     : ((kk * 4 + fg) ^ (row & 7));
                af[mi] = *(const f16x8*)(&lA[buf][row * BK + pc * 8]);
            }
#pragma unroll
            for (int ni = 0; ni < 2; ++ni) {
                int row = colBase + ni * 16 + fr;
                int pc  = (BK == 32) ? (fg ^ ((row >> 1) & 3))
                                     : ((kk * 4 + fg) ^ (row & 7));
                bfv[ni] = *(const f16x8*)(&lB[buf][row * BK + pc * 8]);
            }
#pragma unroll
            for (int mi = 0; mi < 4; ++mi)
#pragma unroll
                for (int ni = 0; ni < 2; ++ni)
                    acc[mi][ni] = mfma16(af[mi], bfv[ni], acc[mi][ni]);
        }
    }

    // ---------------- epilogue ----------------
    // C/D layout: col = lane&15, row = 4*(lane>>4)+reg  [m89]
    const int mat0 = (EPI == 0) ? (n0 / 768) : 0;   // block-uniform

    if constexpr (EPI == 0 || EPI == 2) {
        if (EPI == 2 || mat0 < 2) {
            // LDS-bounce (stride 136): full-line u16x8 global stores
            unsigned short* sm = smem;
            __syncthreads();
#pragma unroll
            for (int mi = 0; mi < 4; ++mi)
#pragma unroll
                for (int ni = 0; ni < 2; ++ni) {
                    const int lcol = colBase + ni * 16 + fr;
                    const int colg = n0 + lcol;
#pragma unroll
                    for (int reg = 0; reg < 4; ++reg) {
                        const int lrow = mi * 16 + fg * 4 + reg;
                        float val = acc[mi][ni][reg] + p2[colg];
                        if (EPI == 2)
                            val = 0.5f * val * (1.0f + erff(val * 0.70710678118654752f));
                        sm[lrow * 136 + lcol] = f2h(val);
                    }
                }
            __syncthreads();
#pragma unroll
            for (int it = 0; it < 4; ++it) {
                const int e = it * 256 + tid;       // 1024 chunks of 8
                const int lrow = e >> 4, cch = e & 15;
                const int grow = m0 + lrow;
                if (grow >= M) continue;
                const u16x8 v = *(const u16x8*)(&sm[lrow * 136 + cch * 8]);
                if (EPI == 2) {
                    *(u16x8*)(p1 + (size_t)grow * 3072 + n0 + cch * 8) = v;
                } else {
                    const int colg = n0 + cch * 8;
                    const int w = colg - mat0 * 768;
                    const int h = w >> 6, d = w & 63;
                    const int b = grow / 197, s = grow - b * 197;
                    unsigned short* dst = (mat0 == 0) ? p1 : p4;
                    *(u16x8*)(dst + ((((size_t)b * 12 + h) * 197 + s) * 64 + d)) = v;
                }
            }
        } else {
            // V (mat==2): transposed target, scalar path
#pragma unroll
            for (int mi = 0; mi < 4; ++mi)
#pragma unroll
                for (int ni = 0; ni < 2; ++ni) {
                    const int col = n0 + colBase + ni * 16 + fr;
                    const int w = col - 1536;
                    const int h = w >> 6, d = w & 63;
#pragma unroll
                    for (int reg = 0; reg < 4; ++reg) {
                        const int row = m0 + mi * 16 + fg * 4 + reg;
                        if (row >= M) continue;
                        const int b = row / 197, s = row - b * 197;
                        float val = acc[mi][ni][reg] + p2[col];
                        p5[(((size_t)b * 12 + h) * 64 + d) * 208 + s] = f2h(val);
                    }
                }
        }
    } else {
#pragma unroll
        for (int mi = 0; mi < 4; ++mi) {
#pragma unroll
            for (int ni = 0; ni < 2; ++ni) {
                const int col = n0 + colBase + ni * 16 + fr;
#pragma unroll
                for (int reg = 0; reg < 4; ++reg) {
                    const int row = m0 + mi * 16 + fg * 4 + reg;
                    if (row >= M) continue;
                    const float v = acc[mi][ni][reg];
                    if constexpr (EPI == 1 || EPI == 3) {
                        size_t idx = (size_t)row * 768 + col;
                        p0[idx] = p0[idx] + v + p2[col];
                    } else { // EPI == 4
                        int b = row / 196, p = row - b * 196;
                        float val = v + p2[col] + p3[(size_t)(1 + p) * 768 + col];
                        p0[((size_t)(b * 197 + 1 + p)) * 768 + col] = val;
                    }
                }
            }
        }
    }
}

// =====================================================================
// Transpose-convert body: src fp32 [K][N] -> dst f16 [N][K], 64x64 tile.
// =====================================================================
__device__ __forceinline__ void convT_body(const float* __restrict__ src,
                                           unsigned short* __restrict__ dst,
                                           int K, int N, int bx, int by,
                                           float (*t)[65])
{
    const int tid = threadIdx.x;
    const int n0 = bx * 64, k0 = by * 64;
    int r = tid >> 4, cq = tid & 15;
#pragma unroll
    for (int i = 0; i < 4; ++i) {
        f32x4 v = *(const f32x4*)(src + (size_t)(k0 + r + i * 16) * N + n0 + cq * 4);
        t[r + i * 16][cq * 4 + 0] = v.x;
        t[r + i * 16][cq * 4 + 1] = v.y;
        t[r + i * 16][cq * 4 + 2] = v.z;
        t[r + i * 16][cq * 4 + 3] = v.w;
    }
    __syncthreads();
    int nl = tid >> 2, kq = tid & 3;
    u16x8 o0, o1;
#pragma unroll
    for (int j = 0; j < 8; ++j) {
        o0[j] = f2h(t[kq * 16 + j][nl]);
        o1[j] = f2h(t[kq * 16 + 8 + j][nl]);
    }
    unsigned short* d = dst + (size_t)(n0 + nl) * K + k0 + kq * 16;
    *(u16x8*)(d)     = o0;
    *(u16x8*)(d + 8) = o1;
}

// prep block decode (pid in [0,1729)): all 6 weight transposes + bias pack
__device__ __forceinline__ void prep_block(int pid,
            const float* __restrict__ wq, const float* __restrict__ wk,
            const float* __restrict__ wv, const float* __restrict__ wo,
            const float* __restrict__ w1, const float* __restrict__ w2,
            const float* __restrict__ bq, const float* __restrict__ bk,
            const float* __restrict__ bv,
            unsigned short* __restrict__ wqkvT, unsigned short* __restrict__ woT,
            unsigned short* __restrict__ w1T, unsigned short* __restrict__ w2T,
            float* __restrict__ bqkv, float (*t)[65])
{
    if (pid == 1728) {
        for (int c = threadIdx.x; c < 2304; c += 256) {
            int m = c / 768, w = c - m * 768;
            bqkv[c] = (m == 0) ? bq[w] : (m == 1 ? bk[w] : bv[w]);
        }
        return;
    }
    const float* src; unsigned short* dst; int K, N, bx, by;
    if (pid < 576) {
        int mat = pid / 144, r = pid - mat * 144;
        K = 768; N = 768; bx = r % 12; by = r / 12;
        if (mat == 0)      { src = wq; dst = wqkvT; }
        else if (mat == 1) { src = wk; dst = wqkvT + 768ull * 768; }
        else if (mat == 2) { src = wv; dst = wqkvT + 1536ull * 768; }
        else               { src = wo; dst = woT; }
    } else if (pid < 1152) {
        int r = pid - 576; K = 768; N = 3072; bx = r % 48; by = r / 48;
        src = w1; dst = w1T;
    } else {
        int r = pid - 1152; K = 3072; N = 768; bx = r % 12; by = r / 12;
        src = w2; dst = w2T;
    }
    convT_body(src, dst, K, N, bx, by, t);
}

// standalone prep (layer 0, pre-loop)
__global__ __launch_bounds__(256)
void prep_k(const float* __restrict__ wq, const float* __restrict__ wk,
            const float* __restrict__ wv, const float* __restrict__ wo,
            const float* __restrict__ w1, const float* __restrict__ w2,
            const float* __restrict__ bq, const float* __restrict__ bk,
            const float* __restrict__ bv,
            unsigned short* __restrict__ wqkvT, unsigned short* __restrict__ woT,
            unsigned short* __restrict__ w1T, unsigned short* __restrict__ w2T,
            float* __restrict__ bqkv)
{
    __shared__ float t[64][65];
    prep_block(blockIdx.x, wq, wk, wv, wo, w1, w2, bq, bk, bv,
               wqkvT, woT, w1T, w2T, bqkv, t);
}

// =====================================================================
// attn_prep_k: flattened grid = 2688 attn blocks + nprep prep blocks.
// attn: no K/V LDS staging; K from global (L2), V pre-transposed.
// prep blocks transpose layer-(l+1) weights into the other dbuf set.
// =====================================================================
__global__ __launch_bounds__(256, 4)
void attn_prep_k(const unsigned short* __restrict__ qb, const unsigned short* __restrict__ kb,
                 const unsigned short* __restrict__ vt, unsigned short* __restrict__ ao,
                 const float* __restrict__ wq, const float* __restrict__ wk,
                 const float* __restrict__ wv, const float* __restrict__ wo,
                 const float* __restrict__ w1, const float* __restrict__ w2,
                 const float* __restrict__ bq, const float* __restrict__ bk,
                 const float* __restrict__ bv,
                 unsigned short* __restrict__ wqkvT, unsigned short* __restrict__ woT,
                 unsigned short* __restrict__ w1T, unsigned short* __restrict__ w2T,
                 float* __restrict__ bqkv)
{
    __shared__ float smbuf[32 * 210 + 32];   // attn sc+rinv / prep tile

    const int bid = blockIdx.x;
    if (bid >= 2688) {
        prep_block(bid - 2688, wq, wk, wv, wo, w1, w2, bq, bk, bv,
                   wqkvT, woT, w1T, w2T, bqkv,
                   reinterpret_cast<float(*)[65]>(smbuf));
        return;
    }

    float* sc   = smbuf;
    float* rinv = smbuf + 32 * 210;

    const int bh = bid % 384;
    const int qt = bid / 384;
    const int b = bh / 12, h = bh - b * 12;
    const unsigned short* qh  = qb + (size_t)bh * 197 * 64;
    const unsigned short* kh  = kb + (size_t)bh * 197 * 64;
    const unsigned short* vth = vt + (size_t)bh * 64 * 208;
    const int tid = threadIdx.x, lane = tid & 63, wid = tid >> 6;
    const int fr = lane & 15, fg = lane >> 4;

    f16x8 qf[2][2];
#pragma unroll
    for (int mi = 0; mi < 2; ++mi)
#pragma unroll
        for (int kc = 0; kc < 2; ++kc) {
            int s = qt * 32 + mi * 16 + fr; if (s > 196) s = 196;
            qf[mi][kc] = *(const f16x8*)(qh + (size_t)s * 64 + kc * 32 + fg * 8);
        }

    for (int nt = wid; nt < 13; nt += 4) {
        f32x4 a0 = (f32x4){0.f,0.f,0.f,0.f}, a1 = a0;
        int rs = nt * 16 + fr; if (rs > 196) rs = 196;
#pragma unroll
        for (int kc = 0; kc < 2; ++kc) {
            f16x8 kf = *(const f16x8*)(kh + (size_t)rs * 64 + kc * 32 + fg * 8);
            a0 = mfma16(qf[0][kc], kf, a0);
            a1 = mfma16(qf[1][kc], kf, a1);
        }
        int ccol = nt * 16 + fr;
        bool valid = (ccol < 197);
#pragma unroll
        for (int reg = 0; reg < 4; ++reg) {
            int mr = fg * 4 + reg;
            sc[mr * 210 + ccol]        = valid ? a0[reg] * 0.125f : -1e30f;
            sc[(16 + mr) * 210 + ccol] = valid ? a1[reg] * 0.125f : -1e30f;
        }
    }
    __syncthreads();

    {
        int row = tid >> 3, j = tid & 7;
        float m = -1e30f;
        for (int c = j; c < 208; c += 8) m = fmaxf(m, sc[row * 210 + c]);
#pragma unroll
        for (int o = 1; o < 8; o <<= 1) m = fmaxf(m, __shfl_xor(m, o));
        float sum = 0.f;
        for (int c = j; c < 208; c += 8) {
            float e = __expf(sc[row * 210 + c] - m);
            sc[row * 210 + c] = e;
            sum += e;
        }
#pragma unroll
        for (int o = 1; o < 8; o <<= 1) sum += __shfl_xor(sum, o);
        if (j == 0) rinv[row] = 1.0f / sum;
    }
    __syncthreads();

    f32x4 o0 = (f32x4){0.f,0.f,0.f,0.f}, o1 = o0;
    const int dbase = wid * 16;
    for (int kt = 0; kt < 7; ++kt) {
        int kb8 = kt * 32 + fg * 8;
        f16x8 pa0, pa1, vf;
        if (kb8 >= 208) {
#pragma unroll
            for (int j = 0; j < 8; ++j) { pa0[j] = (_Float16)0.f; pa1[j] = (_Float16)0.f; vf[j] = (_Float16)0.f; }
        } else {
            const float* pr0 = &sc[fr * 210 + kb8];
            const float* pr1 = &sc[(16 + fr) * 210 + kb8];
#pragma unroll
            for (int j = 0; j < 8; ++j) { pa0[j] = (_Float16)pr0[j]; pa1[j] = (_Float16)pr1[j]; }
            vf = *(const f16x8*)(vth + (size_t)(dbase + fr) * 208 + kb8);
        }
        o0 = mfma16(pa0, vf, o0);
        o1 = mfma16(pa1, vf, o1);
    }
#pragma unroll
    for (int reg = 0; reg < 4; ++reg) {
        int mr0 = fg * 4 + reg, s0 = qt * 32 + mr0;
        if (s0 < 197)
            ao[((size_t)(b * 197 + s0)) * 768 + h * 64 + dbase + fr] = f2h(o0[reg] * rinv[mr0]);
        int mr1 = 16 + fg * 4 + reg, s1 = qt * 32 + mr1;
        if (s1 < 197)
            ao[((size_t)(b * 197 + s1)) * 768 + h * 64 + dbase + fr] = f2h(o1[reg] * rinv[mr1]);
    }
}

// =====================================================================
// LayerNorm: fp32 in -> f16 out, one row/block
// =====================================================================
__global__ __launch_bounds__(256, 4)
void ln_k(const float* __restrict__ x, const float* __restrict__ gs,
          const float* __restrict__ gb, unsigned short* __restrict__ out)
{
    const int row = blockIdx.x;
    const int tid = threadIdx.x, lane = tid & 63, wid = tid >> 6;
    const float* xr = x + (size_t)row * 768;
    float v0 = xr[tid], v1 = xr[tid + 256], v2 = xr[tid + 512];
    float s = v0 + v1 + v2;
    float q = v0 * v0 + v1 * v1 + v2 * v2;
#pragma unroll
    for (int o = 1; o < 64; o <<= 1) { s += __shfl_xor(s, o); q += __shfl_xor(q, o); }
    __shared__ float ws[4], wq[4];
    if (lane == 0) { ws[wid] = s; wq[wid] = q; }
    __syncthreads();
    s = ws[0] + ws[1] + ws[2] + ws[3];
    q = wq[0] + wq[1] + wq[2] + wq[3];
    const float mean = s * (1.0f / 768.0f);
    const float rstd = rsqrtf(q * (1.0f / 768.0f) - mean * mean + 1e-5f);
    unsigned short* orow = out + (size_t)row * 768;
    orow[tid]       = f2h((v0 - mean) * rstd * gs[tid]       + gb[tid]);
    orow[tid + 256] = f2h((v1 - mean) * rstd * gs[tid + 256] + gb[tid + 256]);
    orow[tid + 512] = f2h((v2 - mean) * rstd * gs[tid + 512] + gb[tid + 512]);
}

__global__ __launch_bounds__(256)
void convT_k(const float* __restrict__ src, unsigned short* __restrict__ dst, int K, int N)
{
    __shared__ float t[64][65];
    convT_body(src, dst, K, N, blockIdx.x, blockIdx.y, t);
}

// patches: [6272][768] f16, col = (py*16+px)*3 + c
__global__ __launch_bounds__(256)
void patch_k(const float* __restrict__ img, unsigned short* __restrict__ patches)
{
    const int t = blockIdx.x;
    const int pxy = threadIdx.x;
    const int b = t / 196, pi = t - b * 196;
    const int gy = pi / 14, gx = pi - gy * 14;
    const int py = pxy >> 4, px = pxy & 15;
    const int yy = gy * 16 + py, xx = gx * 16 + px;
    const float* base = img + ((size_t)b * 3 * 224 + yy) * 224 + xx;
    float c0 = base[0];
    float c1 = base[224 * 224];
    float c2 = base[2 * 224 * 224];
    unsigned short* d = patches + (size_t)t * 768 + pxy * 3;
    d[0] = f2h(c0); d[1] = f2h(c1); d[2] = f2h(c2);
}

__global__ void cls_k(const float* __restrict__ cls, const float* __restrict__ pos,
                      float* __restrict__ x)
{
    int c = blockIdx.x * 256 + threadIdx.x;   // 0..767
    int b = blockIdx.y;
    x[((size_t)b * 197) * 768 + c] = cls[c] + pos[c];
}

// final LN on cls row + head matmul. grid (8 n-tiles of 125, 32 b).
__global__ __launch_bounds__(256, 4)
void head_k(const float* __restrict__ x, const float* __restrict__ fs, const float* __restrict__ fb,
            const float* __restrict__ hw, const float* __restrict__ hb, float* __restrict__ out)
{
    __shared__ float xn[768];
    __shared__ float ws[4], wq_[4];
    const int b  = blockIdx.y;
    const int n0 = blockIdx.x * 125;
    const int tid = threadIdx.x, lane = tid & 63, wid = tid >> 6;
    const float* xr = x + (size_t)b * 197 * 768;
    float v0 = xr[tid], v1 = xr[tid + 256], v2 = xr[tid + 512];
    float s = v0 + v1 + v2, q = v0 * v0 + v1 * v1 + v2 * v2;
#pragma unroll
    for (int o = 1; o < 64; o <<= 1) { s += __shfl_xor(s, o); q += __shfl_xor(q, o); }
    if (lane == 0) { ws[wid] = s; wq_[wid] = q; }
    __syncthreads();
    s = ws[0] + ws[1] + ws[2] + ws[3];
    q = wq_[0] + wq_[1] + wq_[2] + wq_[3];
    float mean = s * (1.f / 768.f);
    float rstd = rsqrtf(q * (1.f / 768.f) - mean * mean + 1e-5f);
    xn[tid]       = (v0 - mean) * rstd * fs[tid]       + fb[tid];
    xn[tid + 256] = (v1 - mean) * rstd * fs[tid + 256] + fb[tid + 256];
    xn[tid + 512] = (v2 - mean) * rstd * fs[tid + 512] + fb[tid + 512];
    __syncthreads();

    const int nrel = tid >> 1, half = tid & 1;
    const int n = n0 + nrel;
    float acc = 0.f;
    if (nrel < 125) {
        const float* hp = hw + (size_t)(half * 384) * 1000 + n;
        const float* xp = xn + half * 384;
#pragma unroll 4
        for (int k = 0; k < 384; ++k) acc = fmaf(xp[k], hp[(size_t)k * 1000], acc);
    }
    acc += __shfl_xor(acc, 1);
    if (half == 0 && nrel < 125) out[(size_t)b * 1000 + n] = acc + hb[n];
}

// =====================================================================
extern "C" void kernel_launch(void* const* d_in, const int* in_sizes, int n_in,
                              void* d_out, int out_size, void* d_ws, size_t ws_size,
                              hipStream_t stream)
{
    (void)in_sizes; (void)n_in; (void)out_size; (void)ws_size;
    const float* img    = (const float*)d_in[0];
    const float* proj_w = (const float*)d_in[1];
    const float* proj_b = (const float*)d_in[2];
    const float* cls_t  = (const float*)d_in[3];
    const float* pos    = (const float*)d_in[4];
    const float* ln1_s  = (const float*)d_in[5];
    const float* ln1_b  = (const float*)d_in[6];
    const float* wq     = (const float*)d_in[7];
    const float* bq     = (const float*)d_in[8];
    const float* wk     = (const float*)d_in[9];
    const float* bk     = (const float*)d_in[10];
    const float* wv     = (const float*)d_in[11];
    const float* bv     = (const float*)d_in[12];
    const float* wo     = (const float*)d_in[13];
    const float* bo     = (const float*)d_in[14];
    const float* ln2_s  = (const float*)d_in[15];
    const float* ln2_b  = (const float*)d_in[16];
    const float* w1     = (const float*)d_in[17];
    const float* b1     = (const float*)d_in[18];
    const float* w2     = (const float*)d_in[19];
    const float* b2     = (const float*)d_in[20];
    const float* fs     = (const float*)d_in[21];
    const float* fb     = (const float*)d_in[22];
    const float* hw     = (const float*)d_in[23];
    const float* hb     = (const float*)d_in[24];

    char* ws = (char*)d_ws;
    size_t off = 0;
    auto alloc = [&](size_t bytes) -> char* {
        char* r = ws + off;
        off += (bytes + 255) & ~(size_t)255;
        return r;
    };
    // double-buffered transposed-weight sets (layer parity)
    unsigned short* wqkvT[2]; unsigned short* woT[2];
    unsigned short* w1T[2];   unsigned short* w2T[2];
    float* bqkv[2];
    for (int s = 0; s < 2; ++s) {
        wqkvT[s] = (unsigned short*)alloc(2304ull * 768 * 2);
        woT[s]   = (unsigned short*)alloc(768ull * 768 * 2);
        w1T[s]   = (unsigned short*)alloc(3072ull * 768 * 2);
        w2T[s]   = (unsigned short*)alloc(768ull * 3072 * 2);
        bqkv[s]  = (float*)alloc(2304 * 4);
    }
    unsigned short* projT = (unsigned short*)alloc(768ull * 768 * 2);
    float*          x     = (float*)alloc(6304ull * 768 * 4);
    unsigned short* xn    = (unsigned short*)alloc(6304ull * 768 * 2);
    unsigned short* qbuf  = (unsigned short*)alloc(4841472ull * 2);
    unsigned short* kbuf  = (unsigned short*)alloc(4841472ull * 2);
    unsigned short* vbufT = (unsigned short*)alloc(384ull * 64 * 208 * 2); // [bh][d][208]
    unsigned short* aob   = (unsigned short*)alloc(6304ull * 768 * 2);
    unsigned short* hbuf  = (unsigned short*)alloc(6304ull * 3072 * 2);
    unsigned short* patches = hbuf; // alias: only used before layer loop

    // ---- patch embedding + layer-0 weight prep ----
    convT_k<<<dim3(12, 12), 256, 0, stream>>>(proj_w, projT, 768, 768);
    patch_k<<<dim3(6272), 256, 0, stream>>>(img, patches);
    prep_k<<<dim3(1729), 256, 0, stream>>>(
        wq, wk, wv, wo, w1, w2, bq, bk, bv,
        wqkvT[0], woT[0], w1T[0], w2T[0], bqkv[0]);
    gemm_k<4, 32><<<dim3(6, 98), 256, 0, stream>>>(patches, projT, 6272, 768, 768,
                                                   x, nullptr, proj_b, pos, nullptr, nullptr);
    cls_k<<<dim3(3, 32), 256, 0, stream>>>(cls_t, pos, x);

    // ---- transformer layers ----
    for (int l = 0; l < 12; ++l) {
        const int set = l & 1, nxt = set ^ 1;
        const int lp  = (l < 11) ? l + 1 : 11;       // prep source layer
        const int nprep = (l < 11) ? 1729 : 0;

        ln_k<<<dim3(6304), 256, 0, stream>>>(x, ln1_s + l * 768, ln1_b + l * 768, xn);
        gemm_k<0, 32><<<dim3(18, 99), 256, 0, stream>>>(xn, wqkvT[set], 6304, 768, 2304,
                                                        nullptr, qbuf, bqkv[set], nullptr, kbuf, vbufT);
        attn_prep_k<<<dim3(2688 + nprep), 256, 0, stream>>>(
            qbuf, kbuf, vbufT, aob,
            wq + (size_t)lp * 768 * 768, wk + (size_t)lp * 768 * 768,
            wv + (size_t)lp * 768 * 768, wo + (size_t)lp * 768 * 768,
            w1 + (size_t)lp * 768 * 3072, w2 + (size_t)lp * 3072 * 768,
            bq + lp * 768, bk + lp * 768, bv + lp * 768,
            wqkvT[nxt], woT[nxt], w1T[nxt], w2T[nxt], bqkv[nxt]);
        gemm_k<1, 32><<<dim3(6, 99), 256, 0, stream>>>(aob, woT[set], 6304, 768, 768,
                                                       x, nullptr, bo + l * 768, nullptr, nullptr, nullptr);
        ln_k<<<dim3(6304), 256, 0, stream>>>(x, ln2_s + l * 768, ln2_b + l * 768, xn);
        gemm_k<2, 32><<<dim3(24, 99), 256, 0, stream>>>(xn, w1T[set], 6304, 768, 3072,
                                                        nullptr, hbuf, b1 + l * 3072, nullptr, nullptr, nullptr);
        gemm_k<3, 64><<<dim3(6, 99), 256, 0, stream>>>(hbuf, w2T[set], 6304, 3072, 768,
                                                       x, nullptr, b2 + l * 768, nullptr, nullptr, nullptr);
    }

    // ---- final LN (cls rows) + classifier head ----
    head_k<<<dim3(8, 32), 256, 0, stream>>>(x, fs, fb, hw, hb, (float*)d_out);
}

// Round 20
// 2889.636 us; speedup vs baseline: 2.1641x; 1.0509x over previous
//
#include <hip/hip_runtime.h>
#include <stdint.h>

// ---------- types ----------
typedef __attribute__((ext_vector_type(4))) float  f32x4;
typedef __attribute__((ext_vector_type(8))) _Float16 f16x8;
typedef __attribute__((ext_vector_type(8))) unsigned short u16x8;

__device__ __forceinline__ unsigned short f2h(float f) {
    _Float16 h = (_Float16)f;
    union { _Float16 h; unsigned short u; } cv; cv.h = h; return cv.u;
}

__device__ __forceinline__ f32x4 mfma16(f16x8 a, f16x8 b, f32x4 c) {
    return __builtin_amdgcn_mfma_f32_16x16x32_f16(a, b, c, 0, 0, 0);
}

// async global->LDS, 16B per lane. LDS dest is wave-uniform base; HW writes
// lane i at base + i*16.
__device__ __forceinline__ void async16(const unsigned short* g, unsigned short* l) {
    __builtin_amdgcn_global_load_lds(
        (const __attribute__((address_space(1))) unsigned int*)g,
        (__attribute__((address_space(3))) unsigned int*)l,
        16, 0, 0);
}

// =====================================================================
// GEMM: C(MxN) = A(MxK,f16 rowmajor) * Bw(NxK,f16 rowmajor == W^T)
// BM=64 x BN=128, 4 waves x 64x32 sub-tile, 2-buffer __syncthreads loop.
// BK template: 32 (measured best for K=768) / 64 (best for K=3072).
// Both A and B LDS-staged. f16-output epilogues (EPI 0 q/k, EPI 2) use
// an LDS-bounce (stride 136) so global stores are full-line u16x8.
// EPI 0 V path (R20): column-major LDS bounce (sm[col*68+row]) + lane=s
// stores -> each wave writes 64 consecutive u16 (2 full lines), fixing
// the stride-416B scatter RMW. LN stays standalone (R18 lesson).
// EPI 0: QKV scatter+bias (V transposed [bh][d][208])
// EPI 1/3: x += C + bias    EPI 2: gelu    EPI 4: patch: x = C + b + pos
// =====================================================================
template<int EPI, int BK>
__global__ __launch_bounds__(256, (BK == 32 ? 4 : 3))
void gemm_k(const unsigned short* __restrict__ A, const unsigned short* __restrict__ Bw,
            int M, int K, int N,
            float* __restrict__ p0, unsigned short* __restrict__ p1,
            const float* __restrict__ p2, const float* __restrict__ p3,
            unsigned short* __restrict__ p4, unsigned short* __restrict__ p5)
{
    constexpr int SMSTG = 2 * 64 * BK + 2 * 128 * BK;  // lA | lB staging (u16)
    constexpr int SMU   = (EPI == 0 || EPI == 2)
                          ? (SMSTG > 128 * 68 ? SMSTG : 128 * 68)   // bounce union
                          : SMSTG;
    __shared__ unsigned short smem[SMU];
    unsigned short (*lA)[64 * BK]  = (unsigned short(*)[64 * BK])smem;
    unsigned short (*lB)[128 * BK] = (unsigned short(*)[128 * BK])(smem + 2 * 64 * BK);
    const int tid  = threadIdx.x;
    const int lane = tid & 63;
    const int wid  = tid >> 6;

    // ---- XCD-bijective swizzle (m204) ----
    const int gx  = gridDim.x;
    const int nwg = gx * gridDim.y;
    const int lin = blockIdx.y * gx + blockIdx.x;
    const int q = nwg >> 3, r = nwg & 7;
    const int xcd = lin & 7, i = lin >> 3;
    const int wg  = (xcd < r ? xcd * (q + 1) : r * (q + 1) + (xcd - r) * q) + i;
    const int m0 = (wg / gx) * 64;
    const int n0 = (wg % gx) * 128;

    const int colBase = wid * 32;          // wave's 32-col window
    const int fr = lane & 15, fg = lane >> 4;

    f32x4 acc[4][2];
#pragma unroll
    for (int a = 0; a < 4; ++a)
#pragma unroll
        for (int b = 0; b < 2; ++b) acc[a][b] = (f32x4){0.f, 0.f, 0.f, 0.f};

    const int nk = K / BK;
    constexpr int CPR = BK / 8;            // 16B chunks per row (4 or 8)
    constexpr int ACH = 64 * CPR;          // A chunks (256 or 512)
    constexpr int NH  = (ACH + 128 * CPR) / 256;  // stage iters (3 or 6)

    auto stage = [&](int buf, int kt) {
        const int k0 = kt * BK;
#pragma unroll
        for (int h = 0; h < NH; ++h) {
            const int c = h * 256 + tid;
            const int wbase = h * 256 + wid * 64;
            if (c < ACH) {
                const int row = c / CPR, kc = c % CPR;
                const int gkc = (BK == 32) ? (kc ^ ((row >> 1) & 3)) : (kc ^ (row & 7));
                int ar = m0 + row; if (ar > M - 1) ar = M - 1;
                async16(A + (size_t)ar * K + k0 + gkc * 8,
                        &lA[buf][(size_t)wbase * 8]);
            } else {
                const int cb = c - ACH;
                const int row = cb / CPR, kc = cb % CPR;
                const int gkc = (BK == 32) ? (kc ^ ((row >> 1) & 3)) : (kc ^ (row & 7));
                async16(Bw + (size_t)(n0 + row) * K + k0 + gkc * 8,
                        &lB[buf][(size_t)(wbase - ACH) * 8]);
            }
        }
    };

    stage(0, 0);
    for (int kt = 0; kt < nk; ++kt) {
        __syncthreads();                   // drains vmcnt(0): buf ready
        if (kt + 1 < nk) stage((kt + 1) & 1, kt + 1);
        const int buf = kt & 1;
#pragma unroll
        for (int kk = 0; kk < BK / 32; ++kk) {   // k ascending
            f16x8 af[4], bfv[2];
#pragma unroll
            for (int mi = 0; mi < 4; ++mi) {
                int row = mi * 16 + fr;
                int pc  = (BK == 32) ? (fg ^ ((row >> 1) & 3))
                                     : ((kk * 4 + fg) ^ (row & 7));
                af[mi] = *(const f16x8*)(&lA[buf][row * BK + pc * 8]);
            }
#pragma unroll
            for (int ni = 0; ni < 2; ++ni) {
                int row = colBase + ni * 16 + fr;
                int pc  = (BK == 32) ? (fg ^ ((row >> 1) & 3))
                                     : ((kk * 4 + fg) ^ (row & 7));
                bfv[ni] = *(const f16x8*)(&lB[buf][row * BK + pc * 8]);
            }
#pragma unroll
            for (int mi = 0; mi < 4; ++mi)
#pragma unroll
                for (int ni = 0; ni < 2; ++ni)
                    acc[mi][ni] = mfma16(af[mi], bfv[ni], acc[mi][ni]);
        }
    }

    // ---------------- epilogue ----------------
    // C/D layout: col = lane&15, row = 4*(lane>>4)+reg  [m89]
    const int mat0 = (EPI == 0) ? (n0 / 768) : 0;   // block-uniform

    if constexpr (EPI == 0 || EPI == 2) {
        if (EPI == 2 || mat0 < 2) {
            // LDS-bounce (stride 136): full-line u16x8 global stores
            unsigned short* sm = smem;
            __syncthreads();
#pragma unroll
            for (int mi = 0; mi < 4; ++mi)
#pragma unroll
                for (int ni = 0; ni < 2; ++ni) {
                    const int lcol = colBase + ni * 16 + fr;
                    const int colg = n0 + lcol;
#pragma unroll
                    for (int reg = 0; reg < 4; ++reg) {
                        const int lrow = mi * 16 + fg * 4 + reg;
                        float val = acc[mi][ni][reg] + p2[colg];
                        if (EPI == 2)
                            val = 0.5f * val * (1.0f + erff(val * 0.70710678118654752f));
                        sm[lrow * 136 + lcol] = f2h(val);
                    }
                }
            __syncthreads();
#pragma unroll
            for (int it = 0; it < 4; ++it) {
                const int e = it * 256 + tid;       // 1024 chunks of 8
                const int lrow = e >> 4, cch = e & 15;
                const int grow = m0 + lrow;
                if (grow >= M) continue;
                const u16x8 v = *(const u16x8*)(&sm[lrow * 136 + cch * 8]);
                if (EPI == 2) {
                    *(u16x8*)(p1 + (size_t)grow * 3072 + n0 + cch * 8) = v;
                } else {
                    const int colg = n0 + cch * 8;
                    const int w = colg - mat0 * 768;
                    const int h = w >> 6, d = w & 63;
                    const int b = grow / 197, s = grow - b * 197;
                    unsigned short* dst = (mat0 == 0) ? p1 : p4;
                    *(u16x8*)(dst + ((((size_t)b * 12 + h) * 197 + s) * 64 + d)) = v;
                }
            }
        } else {
            // V (mat==2): column-major bounce + lane=s coalesced stores.
            // sm[col*68 + row]: write banks 2-way (stride 68), read
            // conflict-free (lane-consecutive rows), wave writes 64
            // consecutive u16 -> 2 full 64B lines per store op.
            unsigned short* sm = smem;
            __syncthreads();
#pragma unroll
            for (int mi = 0; mi < 4; ++mi)
#pragma unroll
                for (int ni = 0; ni < 2; ++ni) {
                    const int lcol = colBase + ni * 16 + fr;
                    const int colg = n0 + lcol;
#pragma unroll
                    for (int reg = 0; reg < 4; ++reg) {
                        const int lrow = mi * 16 + fg * 4 + reg;
                        sm[lcol * 68 + lrow] = f2h(acc[mi][ni][reg] + p2[colg]);
                    }
                }
            __syncthreads();
            const int srow = lane;                  // lane = local row (s-dir)
            const int grow = m0 + srow;
            if (grow < M) {
                const int b = grow / 197, s = grow - b * 197;
#pragma unroll
                for (int it = 0; it < 32; ++it) {
                    const int c = (tid >> 6) + it * 4;        // 0..127
                    const int w = n0 + c - 1536;
                    const int h = w >> 6, d = w & 63;
                    p5[(((size_t)b * 12 + h) * 64 + d) * 208 + s] = sm[c * 68 + srow];
                }
            }
        }
    } else {
#pragma unroll
        for (int mi = 0; mi < 4; ++mi) {
#pragma unroll
            for (int ni = 0; ni < 2; ++ni) {
                const int col = n0 + colBase + ni * 16 + fr;
#pragma unroll
                for (int reg = 0; reg < 4; ++reg) {
                    const int row = m0 + mi * 16 + fg * 4 + reg;
                    if (row >= M) continue;
                    const float v = acc[mi][ni][reg];
                    if constexpr (EPI == 1 || EPI == 3) {
                        size_t idx = (size_t)row * 768 + col;
                        p0[idx] = p0[idx] + v + p2[col];
                    } else { // EPI == 4
                        int b = row / 196, p = row - b * 196;
                        float val = v + p2[col] + p3[(size_t)(1 + p) * 768 + col];
                        p0[((size_t)(b * 197 + 1 + p)) * 768 + col] = val;
                    }
                }
            }
        }
    }
}

// =====================================================================
// Transpose-convert body: src fp32 [K][N] -> dst f16 [N][K], 64x64 tile.
// =====================================================================
__device__ __forceinline__ void convT_body(const float* __restrict__ src,
                                           unsigned short* __restrict__ dst,
                                           int K, int N, int bx, int by,
                                           float (*t)[65])
{
    const int tid = threadIdx.x;
    const int n0 = bx * 64, k0 = by * 64;
    int r = tid >> 4, cq = tid & 15;
#pragma unroll
    for (int i = 0; i < 4; ++i) {
        f32x4 v = *(const f32x4*)(src + (size_t)(k0 + r + i * 16) * N + n0 + cq * 4);
        t[r + i * 16][cq * 4 + 0] = v.x;
        t[r + i * 16][cq * 4 + 1] = v.y;
        t[r + i * 16][cq * 4 + 2] = v.z;
        t[r + i * 16][cq * 4 + 3] = v.w;
    }
    __syncthreads();
    int nl = tid >> 2, kq = tid & 3;
    u16x8 o0, o1;
#pragma unroll
    for (int j = 0; j < 8; ++j) {
        o0[j] = f2h(t[kq * 16 + j][nl]);
        o1[j] = f2h(t[kq * 16 + 8 + j][nl]);
    }
    unsigned short* d = dst + (size_t)(n0 + nl) * K + k0 + kq * 16;
    *(u16x8*)(d)     = o0;
    *(u16x8*)(d + 8) = o1;
}

// prep block decode (pid in [0,1729)): all 6 weight transposes + bias pack
__device__ __forceinline__ void prep_block(int pid,
            const float* __restrict__ wq, const float* __restrict__ wk,
            const float* __restrict__ wv, const float* __restrict__ wo,
            const float* __restrict__ w1, const float* __restrict__ w2,
            const float* __restrict__ bq, const float* __restrict__ bk,
            const float* __restrict__ bv,
            unsigned short* __restrict__ wqkvT, unsigned short* __restrict__ woT,
            unsigned short* __restrict__ w1T, unsigned short* __restrict__ w2T,
            float* __restrict__ bqkv, float (*t)[65])
{
    if (pid == 1728) {
        for (int c = threadIdx.x; c < 2304; c += 256) {
            int m = c / 768, w = c - m * 768;
            bqkv[c] = (m == 0) ? bq[w] : (m == 1 ? bk[w] : bv[w]);
        }
        return;
    }
    const float* src; unsigned short* dst; int K, N, bx, by;
    if (pid < 576) {
        int mat = pid / 144, r = pid - mat * 144;
        K = 768; N = 768; bx = r % 12; by = r / 12;
        if (mat == 0)      { src = wq; dst = wqkvT; }
        else if (mat == 1) { src = wk; dst = wqkvT + 768ull * 768; }
        else if (mat == 2) { src = wv; dst = wqkvT + 1536ull * 768; }
        else               { src = wo; dst = woT; }
    } else if (pid < 1152) {
        int r = pid - 576; K = 768; N = 3072; bx = r % 48; by = r / 48;
        src = w1; dst = w1T;
    } else {
        int r = pid - 1152; K = 3072; N = 768; bx = r % 12; by = r / 12;
        src = w2; dst = w2T;
    }
    convT_body(src, dst, K, N, bx, by, t);
}

// standalone prep (layer 0, pre-loop)
__global__ __launch_bounds__(256)
void prep_k(const float* __restrict__ wq, const float* __restrict__ wk,
            const float* __restrict__ wv, const float* __restrict__ wo,
            const float* __restrict__ w1, const float* __restrict__ w2,
            const float* __restrict__ bq, const float* __restrict__ bk,
            const float* __restrict__ bv,
            unsigned short* __restrict__ wqkvT, unsigned short* __restrict__ woT,
            unsigned short* __restrict__ w1T, unsigned short* __restrict__ w2T,
            float* __restrict__ bqkv)
{
    __shared__ float t[64][65];
    prep_block(blockIdx.x, wq, wk, wv, wo, w1, w2, bq, bk, bv,
               wqkvT, woT, w1T, w2T, bqkv, t);
}

// =====================================================================
// attn_prep_k: flattened grid = 2688 attn blocks + nprep prep blocks.
// attn: no K/V LDS staging; K from global (L2), V pre-transposed.
// prep blocks transpose layer-(l+1) weights into the other dbuf set.
// =====================================================================
__global__ __launch_bounds__(256, 4)
void attn_prep_k(const unsigned short* __restrict__ qb, const unsigned short* __restrict__ kb,
                 const unsigned short* __restrict__ vt, unsigned short* __restrict__ ao,
                 const float* __restrict__ wq, const float* __restrict__ wk,
                 const float* __restrict__ wv, const float* __restrict__ wo,
                 const float* __restrict__ w1, const float* __restrict__ w2,
                 const float* __restrict__ bq, const float* __restrict__ bk,
                 const float* __restrict__ bv,
                 unsigned short* __restrict__ wqkvT, unsigned short* __restrict__ woT,
                 unsigned short* __restrict__ w1T, unsigned short* __restrict__ w2T,
                 float* __restrict__ bqkv)
{
    __shared__ float smbuf[32 * 210 + 32];   // attn sc+rinv / prep tile

    const int bid = blockIdx.x;
    if (bid >= 2688) {
        prep_block(bid - 2688, wq, wk, wv, wo, w1, w2, bq, bk, bv,
                   wqkvT, woT, w1T, w2T, bqkv,
                   reinterpret_cast<float(*)[65]>(smbuf));
        return;
    }

    float* sc   = smbuf;
    float* rinv = smbuf + 32 * 210;

    const int bh = bid % 384;
    const int qt = bid / 384;
    const int b = bh / 12, h = bh - b * 12;
    const unsigned short* qh  = qb + (size_t)bh * 197 * 64;
    const unsigned short* kh  = kb + (size_t)bh * 197 * 64;
    const unsigned short* vth = vt + (size_t)bh * 64 * 208;
    const int tid = threadIdx.x, lane = tid & 63, wid = tid >> 6;
    const int fr = lane & 15, fg = lane >> 4;

    f16x8 qf[2][2];
#pragma unroll
    for (int mi = 0; mi < 2; ++mi)
#pragma unroll
        for (int kc = 0; kc < 2; ++kc) {
            int s = qt * 32 + mi * 16 + fr; if (s > 196) s = 196;
            qf[mi][kc] = *(const f16x8*)(qh + (size_t)s * 64 + kc * 32 + fg * 8);
        }

    for (int nt = wid; nt < 13; nt += 4) {
        f32x4 a0 = (f32x4){0.f,0.f,0.f,0.f}, a1 = a0;
        int rs = nt * 16 + fr; if (rs > 196) rs = 196;
#pragma unroll
        for (int kc = 0; kc < 2; ++kc) {
            f16x8 kf = *(const f16x8*)(kh + (size_t)rs * 64 + kc * 32 + fg * 8);
            a0 = mfma16(qf[0][kc], kf, a0);
            a1 = mfma16(qf[1][kc], kf, a1);
        }
        int ccol = nt * 16 + fr;
        bool valid = (ccol < 197);
#pragma unroll
        for (int reg = 0; reg < 4; ++reg) {
            int mr = fg * 4 + reg;
            sc[mr * 210 + ccol]        = valid ? a0[reg] * 0.125f : -1e30f;
            sc[(16 + mr) * 210 + ccol] = valid ? a1[reg] * 0.125f : -1e30f;
        }
    }
    __syncthreads();

    {
        int row = tid >> 3, j = tid & 7;
        float m = -1e30f;
        for (int c = j; c < 208; c += 8) m = fmaxf(m, sc[row * 210 + c]);
#pragma unroll
        for (int o = 1; o < 8; o <<= 1) m = fmaxf(m, __shfl_xor(m, o));
        float sum = 0.f;
        for (int c = j; c < 208; c += 8) {
            float e = __expf(sc[row * 210 + c] - m);
            sc[row * 210 + c] = e;
            sum += e;
        }
#pragma unroll
        for (int o = 1; o < 8; o <<= 1) sum += __shfl_xor(sum, o);
        if (j == 0) rinv[row] = 1.0f / sum;
    }
    __syncthreads();

    f32x4 o0 = (f32x4){0.f,0.f,0.f,0.f}, o1 = o0;
    const int dbase = wid * 16;
    for (int kt = 0; kt < 7; ++kt) {
        int kb8 = kt * 32 + fg * 8;
        f16x8 pa0, pa1, vf;
        if (kb8 >= 208) {
#pragma unroll
            for (int j = 0; j < 8; ++j) { pa0[j] = (_Float16)0.f; pa1[j] = (_Float16)0.f; vf[j] = (_Float16)0.f; }
        } else {
            const float* pr0 = &sc[fr * 210 + kb8];
            const float* pr1 = &sc[(16 + fr) * 210 + kb8];
#pragma unroll
            for (int j = 0; j < 8; ++j) { pa0[j] = (_Float16)pr0[j]; pa1[j] = (_Float16)pr1[j]; }
            vf = *(const f16x8*)(vth + (size_t)(dbase + fr) * 208 + kb8);
        }
        o0 = mfma16(pa0, vf, o0);
        o1 = mfma16(pa1, vf, o1);
    }
#pragma unroll
    for (int reg = 0; reg < 4; ++reg) {
        int mr0 = fg * 4 + reg, s0 = qt * 32 + mr0;
        if (s0 < 197)
            ao[((size_t)(b * 197 + s0)) * 768 + h * 64 + dbase + fr] = f2h(o0[reg] * rinv[mr0]);
        int mr1 = 16 + fg * 4 + reg, s1 = qt * 32 + mr1;
        if (s1 < 197)
            ao[((size_t)(b * 197 + s1)) * 768 + h * 64 + dbase + fr] = f2h(o1[reg] * rinv[mr1]);
    }
}

// =====================================================================
// LayerNorm: fp32 in -> f16 out, one row/block
// =====================================================================
__global__ __launch_bounds__(256, 4)
void ln_k(const float* __restrict__ x, const float* __restrict__ gs,
          const float* __restrict__ gb, unsigned short* __restrict__ out)
{
    const int row = blockIdx.x;
    const int tid = threadIdx.x, lane = tid & 63, wid = tid >> 6;
    const float* xr = x + (size_t)row * 768;
    float v0 = xr[tid], v1 = xr[tid + 256], v2 = xr[tid + 512];
    float s = v0 + v1 + v2;
    float q = v0 * v0 + v1 * v1 + v2 * v2;
#pragma unroll
    for (int o = 1; o < 64; o <<= 1) { s += __shfl_xor(s, o); q += __shfl_xor(q, o); }
    __shared__ float ws[4], wq[4];
    if (lane == 0) { ws[wid] = s; wq[wid] = q; }
    __syncthreads();
    s = ws[0] + ws[1] + ws[2] + ws[3];
    q = wq[0] + wq[1] + wq[2] + wq[3];
    const float mean = s * (1.0f / 768.0f);
    const float rstd = rsqrtf(q * (1.0f / 768.0f) - mean * mean + 1e-5f);
    unsigned short* orow = out + (size_t)row * 768;
    orow[tid]       = f2h((v0 - mean) * rstd * gs[tid]       + gb[tid]);
    orow[tid + 256] = f2h((v1 - mean) * rstd * gs[tid + 256] + gb[tid + 256]);
    orow[tid + 512] = f2h((v2 - mean) * rstd * gs[tid + 512] + gb[tid + 512]);
}

__global__ __launch_bounds__(256)
void convT_k(const float* __restrict__ src, unsigned short* __restrict__ dst, int K, int N)
{
    __shared__ float t[64][65];
    convT_body(src, dst, K, N, blockIdx.x, blockIdx.y, t);
}

// patches: [6272][768] f16, col = (py*16+px)*3 + c
__global__ __launch_bounds__(256)
void patch_k(const float* __restrict__ img, unsigned short* __restrict__ patches)
{
    const int t = blockIdx.x;
    const int pxy = threadIdx.x;
    const int b = t / 196, pi = t - b * 196;
    const int gy = pi / 14, gx = pi - gy * 14;
    const int py = pxy >> 4, px = pxy & 15;
    const int yy = gy * 16 + py, xx = gx * 16 + px;
    const float* base = img + ((size_t)b * 3 * 224 + yy) * 224 + xx;
    float c0 = base[0];
    float c1 = base[224 * 224];
    float c2 = base[2 * 224 * 224];
    unsigned short* d = patches + (size_t)t * 768 + pxy * 3;
    d[0] = f2h(c0); d[1] = f2h(c1); d[2] = f2h(c2);
}

__global__ void cls_k(const float* __restrict__ cls, const float* __restrict__ pos,
                      float* __restrict__ x)
{
    int c = blockIdx.x * 256 + threadIdx.x;   // 0..767
    int b = blockIdx.y;
    x[((size_t)b * 197) * 768 + c] = cls[c] + pos[c];
}

// final LN on cls row + head matmul. grid (8 n-tiles of 125, 32 b).
__global__ __launch_bounds__(256, 4)
void head_k(const float* __restrict__ x, const float* __restrict__ fs, const float* __restrict__ fb,
            const float* __restrict__ hw, const float* __restrict__ hb, float* __restrict__ out)
{
    __shared__ float xn[768];
    __shared__ float ws[4], wq_[4];
    const int b  = blockIdx.y;
    const int n0 = blockIdx.x * 125;
    const int tid = threadIdx.x, lane = tid & 63, wid = tid >> 6;
    const float* xr = x + (size_t)b * 197 * 768;
    float v0 = xr[tid], v1 = xr[tid + 256], v2 = xr[tid + 512];
    float s = v0 + v1 + v2, q = v0 * v0 + v1 * v1 + v2 * v2;
#pragma unroll
    for (int o = 1; o < 64; o <<= 1) { s += __shfl_xor(s, o); q += __shfl_xor(q, o); }
    if (lane == 0) { ws[wid] = s; wq_[wid] = q; }
    __syncthreads();
    s = ws[0] + ws[1] + ws[2] + ws[3];
    q = wq_[0] + wq_[1] + wq_[2] + wq_[3];
    float mean = s * (1.f / 768.f);
    float rstd = rsqrtf(q * (1.f / 768.f) - mean * mean + 1e-5f);
    xn[tid]       = (v0 - mean) * rstd * fs[tid]       + fb[tid];
    xn[tid + 256] = (v1 - mean) * rstd * fs[tid + 256] + fb[tid + 256];
    xn[tid + 512] = (v2 - mean) * rstd * fs[tid + 512] + fb[tid + 512];
    __syncthreads();

    const int nrel = tid >> 1, half = tid & 1;
    const int n = n0 + nrel;
    float acc = 0.f;
    if (nrel < 125) {
        const float* hp = hw + (size_t)(half * 384) * 1000 + n;
        const float* xp = xn + half * 384;
#pragma unroll 4
        for (int k = 0; k < 384; ++k) acc = fmaf(xp[k], hp[(size_t)k * 1000], acc);
    }
    acc += __shfl_xor(acc, 1);
    if (half == 0 && nrel < 125) out[(size_t)b * 1000 + n] = acc + hb[n];
}

// =====================================================================
extern "C" void kernel_launch(void* const* d_in, const int* in_sizes, int n_in,
                              void* d_out, int out_size, void* d_ws, size_t ws_size,
                              hipStream_t stream)
{
    (void)in_sizes; (void)n_in; (void)out_size; (void)ws_size;
    const float* img    = (const float*)d_in[0];
    const float* proj_w = (const float*)d_in[1];
    const float* proj_b = (const float*)d_in[2];
    const float* cls_t  = (const float*)d_in[3];
    const float* pos    = (const float*)d_in[4];
    const float* ln1_s  = (const float*)d_in[5];
    const float* ln1_b  = (const float*)d_in[6];
    const float* wq     = (const float*)d_in[7];
    const float* bq     = (const float*)d_in[8];
    const float* wk     = (const float*)d_in[9];
    const float* bk     = (const float*)d_in[10];
    const float* wv     = (const float*)d_in[11];
    const float* bv     = (const float*)d_in[12];
    const float* wo     = (const float*)d_in[13];
    const float* bo     = (const float*)d_in[14];
    const float* ln2_s  = (const float*)d_in[15];
    const float* ln2_b  = (const float*)d_in[16];
    const float* w1     = (const float*)d_in[17];
    const float* b1     = (const float*)d_in[18];
    const float* w2     = (const float*)d_in[19];
    const float* b2     = (const float*)d_in[20];
    const float* fs     = (const float*)d_in[21];
    const float* fb     = (const float*)d_in[22];
    const float* hw     = (const float*)d_in[23];
    const float* hb     = (const float*)d_in[24];

    char* ws = (char*)d_ws;
    size_t off = 0;
    auto alloc = [&](size_t bytes) -> char* {
        char* r = ws + off;
        off += (bytes + 255) & ~(size_t)255;
        return r;
    };
    // double-buffered transposed-weight sets (layer parity)
    unsigned short* wqkvT[2]; unsigned short* woT[2];
    unsigned short* w1T[2];   unsigned short* w2T[2];
    float* bqkv[2];
    for (int s = 0; s < 2; ++s) {
        wqkvT[s] = (unsigned short*)alloc(2304ull * 768 * 2);
        woT[s]   = (unsigned short*)alloc(768ull * 768 * 2);
        w1T[s]   = (unsigned short*)alloc(3072ull * 768 * 2);
        w2T[s]   = (unsigned short*)alloc(768ull * 3072 * 2);
        bqkv[s]  = (float*)alloc(2304 * 4);
    }
    unsigned short* projT = (unsigned short*)alloc(768ull * 768 * 2);
    float*          x     = (float*)alloc(6304ull * 768 * 4);
    unsigned short* xn    = (unsigned short*)alloc(6304ull * 768 * 2);
    unsigned short* qbuf  = (unsigned short*)alloc(4841472ull * 2);
    unsigned short* kbuf  = (unsigned short*)alloc(4841472ull * 2);
    unsigned short* vbufT = (unsigned short*)alloc(384ull * 64 * 208 * 2); // [bh][d][208]
    unsigned short* aob   = (unsigned short*)alloc(6304ull * 768 * 2);
    unsigned short* hbuf  = (unsigned short*)alloc(6304ull * 3072 * 2);
    unsigned short* patches = hbuf; // alias: only used before layer loop

    // ---- patch embedding + layer-0 weight prep ----
    convT_k<<<dim3(12, 12), 256, 0, stream>>>(proj_w, projT, 768, 768);
    patch_k<<<dim3(6272), 256, 0, stream>>>(img, patches);
    prep_k<<<dim3(1729), 256, 0, stream>>>(
        wq, wk, wv, wo, w1, w2, bq, bk, bv,
        wqkvT[0], woT[0], w1T[0], w2T[0], bqkv[0]);
    gemm_k<4, 32><<<dim3(6, 98), 256, 0, stream>>>(patches, projT, 6272, 768, 768,
                                                   x, nullptr, proj_b, pos, nullptr, nullptr);
    cls_k<<<dim3(3, 32), 256, 0, stream>>>(cls_t, pos, x);

    // ---- transformer layers ----
    for (int l = 0; l < 12; ++l) {
        const int set = l & 1, nxt = set ^ 1;
        const int lp  = (l < 11) ? l + 1 : 11;       // prep source layer
        const int nprep = (l < 11) ? 1729 : 0;

        ln_k<<<dim3(6304), 256, 0, stream>>>(x, ln1_s + l * 768, ln1_b + l * 768, xn);
        gemm_k<0, 32><<<dim3(18, 99), 256, 0, stream>>>(xn, wqkvT[set], 6304, 768, 2304,
                                                        nullptr, qbuf, bqkv[set], nullptr, kbuf, vbufT);
        attn_prep_k<<<dim3(2688 + nprep), 256, 0, stream>>>(
            qbuf, kbuf, vbufT, aob,
            wq + (size_t)lp * 768 * 768, wk + (size_t)lp * 768 * 768,
            wv + (size_t)lp * 768 * 768, wo + (size_t)lp * 768 * 768,
            w1 + (size_t)lp * 768 * 3072, w2 + (size_t)lp * 3072 * 768,
            bq + lp * 768, bk + lp * 768, bv + lp * 768,
            wqkvT[nxt], woT[nxt], w1T[nxt], w2T[nxt], bqkv[nxt]);
        gemm_k<1, 32><<<dim3(6, 99), 256, 0, stream>>>(aob, woT[set], 6304, 768, 768,
                                                       x, nullptr, bo + l * 768, nullptr, nullptr, nullptr);
        ln_k<<<dim3(6304), 256, 0, stream>>>(x, ln2_s + l * 768, ln2_b + l * 768, xn);
        gemm_k<2, 32><<<dim3(24, 99), 256, 0, stream>>>(xn, w1T[set], 6304, 768, 3072,
                                                        nullptr, hbuf, b1 + l * 3072, nullptr, nullptr, nullptr);
        gemm_k<3, 64><<<dim3(6, 99), 256, 0, stream>>>(hbuf, w2T[set], 6304, 3072, 768,
                                                       x, nullptr, b2 + l * 768, nullptr, nullptr, nullptr);
    }

    // ---- final LN (cls rows) + classifier head ----
    head_k<<<dim3(8, 32), 256, 0, stream>>>(x, fs, fb, hw, hb, (float*)d_out);
}